// Round 24
// baseline (406.335 us; speedup 1.0000x reference)
//
#include <hip/hip_runtime.h>
#include <hip/hip_bf16.h>

#define DIM   1536
#define HEADS 12
#define HD    128
#define SEQ   4096
#define QSCALE 0.08838834764831845f
#define LOG2E 1.44269504088896f

typedef __attribute__((ext_vector_type(8))) short short8;
typedef __attribute__((ext_vector_type(4))) float f32x4;
typedef __attribute__((ext_vector_type(16))) float f32x16;

__device__ __forceinline__ unsigned short f2bf(float f) {
    __hip_bfloat16 h = __float2bfloat16(f);
    return *reinterpret_cast<unsigned short*>(&h);
}
__device__ __forceinline__ float bf2f(unsigned short u) {
    return __uint_as_float(((unsigned int)u) << 16);
}
__device__ __forceinline__ void async_cp16(void* lds, const void* g) {
    __builtin_amdgcn_global_load_lds(
        (const __attribute__((address_space(1))) unsigned int*)g,
        (__attribute__((address_space(3))) unsigned int*)lds, 16, 0, 0);
}

// ---------------------------------------------------------------------------
// f32 -> bf16 convert, 8 elements/thread. (for wo, post-flash)
// ---------------------------------------------------------------------------
__global__ __launch_bounds__(256) void convert_bf16(
    const float* __restrict__ src, __hip_bfloat16* __restrict__ dst, int n8)
{
    const int i = blockIdx.x * 256 + threadIdx.x;
    if (i >= n8) return;
    const float4 a = *reinterpret_cast<const float4*>(src + (size_t)i * 8);
    const float4 b = *reinterpret_cast<const float4*>(src + (size_t)i * 8 + 4);
    uint4 o;
    o.x = (unsigned int)f2bf(a.x) | ((unsigned int)f2bf(a.y) << 16);
    o.y = (unsigned int)f2bf(a.z) | ((unsigned int)f2bf(a.w) << 16);
    o.z = (unsigned int)f2bf(b.x) | ((unsigned int)f2bf(b.y) << 16);
    o.w = (unsigned int)f2bf(b.z) | ((unsigned int)f2bf(b.w) << 16);
    *reinterpret_cast<uint4*>(dst + (size_t)i * 8) = o;
}

// ---------------------------------------------------------------------------
// Batched f32 -> bf16 convert: x, wq, wk, wv in one launch. (verified r20)
// ---------------------------------------------------------------------------
__global__ __launch_bounds__(256) void convert_all(
    const float* __restrict__ x,  const float* __restrict__ wq,
    const float* __restrict__ wk, const float* __restrict__ wv,
    __hip_bfloat16* __restrict__ xb,  __hip_bfloat16* __restrict__ wqb,
    __hip_bfloat16* __restrict__ wkb, __hip_bfloat16* __restrict__ wvb)
{
    const int i = blockIdx.x * 256 + threadIdx.x;   // grid covers 1671168
    const float* src;
    __hip_bfloat16* dst;
    int off;
    if (i < 786432)            { src = x;  dst = xb;  off = i; }
    else if (i < 1081344)      { src = wq; dst = wqb; off = i - 786432; }
    else if (i < 1376256)      { src = wk; dst = wkb; off = i - 1081344; }
    else                       { src = wv; dst = wvb; off = i - 1376256; }
    const float4 a = *reinterpret_cast<const float4*>(src + (size_t)off * 8);
    const float4 b = *reinterpret_cast<const float4*>(src + (size_t)off * 8 + 4);
    uint4 o;
    o.x = (unsigned int)f2bf(a.x) | ((unsigned int)f2bf(a.y) << 16);
    o.y = (unsigned int)f2bf(a.z) | ((unsigned int)f2bf(a.w) << 16);
    o.z = (unsigned int)f2bf(b.x) | ((unsigned int)f2bf(b.y) << 16);
    o.w = (unsigned int)f2bf(b.z) | ((unsigned int)f2bf(b.w) << 16);
    *reinterpret_cast<uint4*>(dst + (size_t)off * 8) = o;
}

// ---------------------------------------------------------------------------
// GEMM (m97-style, single-buffered — r21/r23 verified best).
// ---------------------------------------------------------------------------
__global__ __launch_bounds__(256) void gemm_qkv(
    const __hip_bfloat16* __restrict__ xb,
    const __hip_bfloat16* __restrict__ wqb, const float* __restrict__ bq,
    const __hip_bfloat16* __restrict__ wkb, const float* __restrict__ bk,
    const __hip_bfloat16* __restrict__ wvb, const float* __restrict__ bv,
    __hip_bfloat16* __restrict__ yq, __hip_bfloat16* __restrict__ yk,
    __hip_bfloat16* __restrict__ vrow)
{
    __shared__ __align__(16) short As[128][32];
    __shared__ __align__(16) short Bs[128][32];
    const int z  = blockIdx.z;
    const __hip_bfloat16* W = (z == 0) ? wqb : (z == 1) ? wkb : wvb;
    const float* bias = (z == 0) ? bq : (z == 1) ? bk : bv;
    __hip_bfloat16* outp = (z == 0) ? yq : (z == 1) ? yk : vrow;
    const int bm0 = blockIdx.x * 128;
    const int bn0 = blockIdx.y * 128;
    const int tid  = threadIdx.x;
    const int lane = tid & 63;
    const int wid  = tid >> 6;
    const int wm = (wid >> 1) * 64;
    const int wn = (wid & 1)  * 64;
    const int fr = lane & 15;
    const int fc = (lane >> 4) * 8;
    const int srow = tid >> 2;
    const int scol = (tid & 3) * 8;

    f32x4 acc[4][4] = {};

    for (int kt = 0; kt < DIM; kt += 32) {
        #pragma unroll
        for (int i = 0; i < 2; i++) {
            async_cp16(&As[i * 64 + (wid << 4)][0],
                       xb + (size_t)(bm0 + i * 64 + srow) * DIM + kt + scol);
            async_cp16(&Bs[i * 64 + (wid << 4)][0],
                       W + (size_t)(bn0 + i * 64 + srow) * DIM + kt + scol);
        }
        __syncthreads();
        short8 af[4], bf8[4];
        #pragma unroll
        for (int m = 0; m < 4; m++) af[m]  = *reinterpret_cast<const short8*>(&As[wm + m * 16 + fr][fc]);
        #pragma unroll
        for (int n = 0; n < 4; n++) bf8[n] = *reinterpret_cast<const short8*>(&Bs[wn + n * 16 + fr][fc]);
        #pragma unroll
        for (int m = 0; m < 4; m++)
            #pragma unroll
            for (int n = 0; n < 4; n++)
                acc[m][n] = __builtin_amdgcn_mfma_f32_16x16x32_bf16(af[m], bf8[n], acc[m][n], 0, 0, 0);
        __syncthreads();
    }

    const int crow0 = bm0 + wm + (lane >> 4) * 4;
    const int ccol0 = bn0 + wn + fr;
    #pragma unroll
    for (int n = 0; n < 4; n++) {
        const int col = ccol0 + n * 16;
        const float bb = bias[col];
        #pragma unroll
        for (int m = 0; m < 4; m++)
            #pragma unroll
            for (int r = 0; r < 4; r++)
                outp[(size_t)(crow0 + m * 16 + r) * DIM + col] =
                    __float2bfloat16(acc[m][n][r] + bb);
    }
}

// ---------------------------------------------------------------------------
// Merged: RMSNorm+RoPE (blocks 0..8191) and V-transpose (8192..9727).
// (unchanged, verified r21)
// ---------------------------------------------------------------------------
__global__ __launch_bounds__(256) void norm_rope_transpose(
    __hip_bfloat16* __restrict__ yq, __hip_bfloat16* __restrict__ yk,
    const float* __restrict__ gq, const float* __restrict__ gk,
    const float* __restrict__ freqs,
    const __hip_bfloat16* __restrict__ vrow, __hip_bfloat16* __restrict__ vT)
{
    __shared__ float red[4];
    __shared__ __align__(16) short tile[64][72];
    const int b = blockIdx.x;
    const int t = threadIdx.x;

    if (b < 8192) {
        const int s = b >> 1;
        const int z = b & 1;
        __hip_bfloat16* y = z ? yk : yq;
        const float* g = z ? gk : gq;

        float xr[3], xi[3];
        float ss = 0.f;
        #pragma unroll
        for (int i = 0; i < 3; i++) {
            const int p = t + i * 256;
            const unsigned int uu = *reinterpret_cast<const unsigned int*>(&y[(size_t)s * DIM + 2 * p]);
            xr[i] = bf2f((unsigned short)(uu & 0xffffu));
            xi[i] = bf2f((unsigned short)(uu >> 16));
            ss += xr[i] * xr[i] + xi[i] * xi[i];
        }
        #pragma unroll
        for (int m = 1; m < 64; m <<= 1) ss += __shfl_xor(ss, m, 64);
        if ((t & 63) == 0) red[t >> 6] = ss;
        __syncthreads();
        const float sum = red[0] + red[1] + red[2] + red[3];
        const float rs = rsqrtf(sum * (1.0f / DIM) + 1e-6f);
        const int f = s >> 8, hh = (s >> 4) & 15, ww = s & 15;
        const float osc = z ? 1.0f : QSCALE;
        #pragma unroll
        for (int i = 0; i < 3; i++) {
            const int p = t + i * 256;
            const int cc = p & 63;
            const int pos = (cc < 22) ? f : (cc < 43) ? hh : ww;
            const float ang = freqs[pos * 64 + cc];
            float sn, cs;
            sincosf(ang, &sn, &cs);
            const float a = xr[i] * rs * g[2 * p];
            const float bb = xi[i] * rs * g[2 * p + 1];
            const unsigned int pk = (unsigned int)f2bf((a * cs - bb * sn) * osc)
                                  | ((unsigned int)f2bf((a * sn + bb * cs) * osc) << 16);
            *reinterpret_cast<unsigned int*>(&y[(size_t)s * DIM + 2 * p]) = pk;
        }
    } else {
        const int tb = b - 8192;
        const int s0 = (tb & 63) * 64;
        const int c0 = (tb >> 6) * 64;
        #pragma unroll
        for (int i = 0; i < 2; i++) {
            const int ch = t + i * 256;
            const int r = ch >> 3, cc = (ch & 7) * 8;
            *reinterpret_cast<int4*>(&tile[r][cc]) =
                *reinterpret_cast<const int4*>(&vrow[(size_t)(s0 + r) * DIM + c0 + cc]);
        }
        __syncthreads();
        #pragma unroll
        for (int i = 0; i < 2; i++) {
            const int ch = t + i * 256;
            const int c = ch & 63, sc = (ch >> 6) * 8;
            unsigned int w0 = (unsigned short)tile[sc + 0][c] | ((unsigned int)(unsigned short)tile[sc + 1][c] << 16);
            unsigned int w1 = (unsigned short)tile[sc + 2][c] | ((unsigned int)(unsigned short)tile[sc + 3][c] << 16);
            unsigned int w2 = (unsigned short)tile[sc + 4][c] | ((unsigned int)(unsigned short)tile[sc + 5][c] << 16);
            unsigned int w3 = (unsigned short)tile[sc + 6][c] | ((unsigned int)(unsigned short)tile[sc + 7][c] << 16);
            int4 val;
            val.x = (int)w0; val.y = (int)w1; val.z = (int)w2; val.w = (int)w3;
            *reinterpret_cast<int4*>(&vT[(size_t)(c0 + c) * SEQ + s0 + sc]) = val;
        }
    }
}

// ---------------------------------------------------------------------------
// Flash attention v14: 2 waves x 64 q-rows (two q-blocks A/B per wave).
// Each K/V fragment read from LDS feeds TWO MFMAs (A/B) -> LDS traffic per
// FLOP halved. 128 threads, __launch_bounds__(128,1) -> up to 512 VGPRs.
// v13 deferred-PV schedule; K dbuf + V triple-buffered (80KB, 2 blocks/CU).
// ---------------------------------------------------------------------------
__global__ __launch_bounds__(128, 1) void flash_attn(
    const __hip_bfloat16* __restrict__ qb,
    const __hip_bfloat16* __restrict__ kb,
    const __hip_bfloat16* __restrict__ vT,
    const int* __restrict__ seq_lens,
    __hip_bfloat16* __restrict__ attno)
{
    __shared__ __align__(16) short Ks[2][64][128];   // 32 KB
    __shared__ __align__(16) short Vs[3][128][64];   // 48 KB
    const int qt = blockIdx.x;
    const int h  = blockIdx.y;
    const int tid = threadIdx.x;
    const int lane = tid & 63;
    const int w = tid >> 6;          // 0/1
    const int q5 = lane & 31;
    const int hi = lane >> 5;
    const int seqlen = seq_lens[0];
    const int swz = (lane & 7) << 4;
    const int NT = SEQ / 64;

    // two q-blocks per wave: rows qA = qt*128 + w*64 + q5, qB = qA + 32
    const int qrowA = qt * 128 + w * 64 + q5;
    const int qrowB = qrowA + 32;
    short8 qfA[8], qfB[8];
    #pragma unroll
    for (int s = 0; s < 8; s++) {
        qfA[s] = *reinterpret_cast<const short8*>(&qb[(size_t)qrowA * DIM + h * HD + s * 16 + hi * 8]);
        qfB[s] = *reinterpret_cast<const short8*>(&qb[(size_t)qrowB * DIM + h * HD + s * 16 + hi * 8]);
    }

    f32x16 oaccA[4] = {}, oaccB[4] = {};
    float mA = -1e30f, lA = 0.f, mB = -1e30f, lB = 0.f;
    unsigned int WpGA[4][4], WpGB[4][4];

    // staging geometry (128 threads; verified v8 constants)
    const int kROW0 = w * 4 + (lane >> 4);                 // 0..7; + i*8
    const int kCOL  = ((lane & 15) ^ kROW0) * 8;
    const int vROW0 = w * 8 + (lane >> 3);                 // 0..15; + i*16
    const int vCOL  = ((lane & 7) ^ (vROW0 & 7)) * 8;

    auto stageK = [&](int tile, int slot) {
        #pragma unroll
        for (int i = 0; i < 8; i++)
            async_cp16(&Ks[slot][i * 8 + w * 4][0],
                       kb + (size_t)(tile * 64 + i * 8 + kROW0) * DIM + h * HD + kCOL);
    };
    auto stageV = [&](int tile, int slot) {
        #pragma unroll
        for (int i = 0; i < 8; i++)
            async_cp16(&Vs[slot][i * 16 + vROW0][0],
                       vT + ((size_t)h * HD + i * 16 + vROW0) * SEQ + tile * 64 + vCOL);
    };
    // QK both q-blocks: each kf read feeds 2 MFMAs
    auto qk = [&](int slot, f32x16* SA, f32x16* SB) {
        const char* Kp = (const char*)&Ks[slot][0][0];
        __builtin_amdgcn_s_setprio(1);
        #pragma unroll
        for (int s = 0; s < 8; s++) {
            #pragma unroll
            for (int kbk = 0; kbk < 2; kbk++) {
                short8 kf = *reinterpret_cast<const short8*>(
                    Kp + (kbk * 32 + q5) * 256 + ((s * 32 + hi * 16) ^ swz));
                SA[kbk] = __builtin_amdgcn_mfma_f32_32x32x16_bf16(kf, qfA[s], SA[kbk], 0, 0, 0);
                SB[kbk] = __builtin_amdgcn_mfma_f32_32x32x16_bf16(kf, qfB[s], SB[kbk], 0, 0, 0);
            }
        }
        __builtin_amdgcn_s_setprio(0);
    };
    // PV both q-blocks: each vf read feeds 2 MFMAs
    auto pv = [&](int slot) {
        const char* Vp = (const char*)&Vs[slot][0][0];
        __builtin_amdgcn_s_setprio(1);
        #pragma unroll
        for (int ks = 0; ks < 4; ks++) {
            int4 pa, pb;
            pa.x = (int)WpGA[ks][0]; pa.y = (int)WpGA[ks][1];
            pa.z = (int)WpGA[ks][2]; pa.w = (int)WpGA[ks][3];
            pb.x = (int)WpGB[ks][0]; pb.y = (int)WpGB[ks][1];
            pb.z = (int)WpGB[ks][2]; pb.w = (int)WpGB[ks][3];
            const short8 pfA = __builtin_bit_cast(short8, pa);
            const short8 pfB = __builtin_bit_cast(short8, pb);
            #pragma unroll
            for (int cb = 0; cb < 4; cb++) {
                short8 vf = *reinterpret_cast<const short8*>(
                    Vp + (cb * 32 + q5) * 128 + ((ks * 32 + hi * 16) ^ swz));
                oaccA[cb] = __builtin_amdgcn_mfma_f32_32x32x16_bf16(vf, pfA, oaccA[cb], 0, 0, 0);
                oaccB[cb] = __builtin_amdgcn_mfma_f32_32x32x16_bf16(vf, pfB, oaccB[cb], 0, 0, 0);
            }
        }
        __builtin_amdgcn_s_setprio(0);
    };
    // softmax one q-block (lane-local m/l; tree reductions) -> WG
    auto softmax_pack = [&](int tt, f32x16& S0, f32x16& S1,
                            float& mm, float& ll, f32x16* oc,
                            unsigned int (*WG)[4]) {
        const int kbase = tt * 64;
        float v[32];
        if (kbase + 64 <= seqlen) {
            #pragma unroll
            for (int r = 0; r < 16; r++) { v[r] = S0[r]; v[16 + r] = S1[r]; }
        } else {
            #pragma unroll
            for (int r = 0; r < 16; r++) {
                const int key0 = kbase + (r & 3) + 8 * (r >> 2) + 4 * hi;
                const float s0 = (key0 < seqlen) ? S0[r] : -1e30f;
                const float s1 = (key0 + 32 < seqlen) ? S1[r] : -1e30f;
                S0[r] = s0; S1[r] = s1;
                v[r] = s0; v[16 + r] = s1;
            }
        }
        #pragma unroll
        for (int st = 16; st >= 1; st >>= 1)
            #pragma unroll
            for (int i = 0; i < st; i++) v[i] = fmaxf(v[i], v[i + st]);
        float tmax = fmaxf(v[0], __shfl_xor(v[0], 32, 64));

        if (!__all(tmax <= mm + 8.0f)) {
            const float mn = fmaxf(mm, tmax);
            const float alpha = exp2f((mm - mn) * LOG2E);
            mm = mn;
            ll *= alpha;
            #pragma unroll
            for (int cb = 0; cb < 4; cb++)
                #pragma unroll
                for (int r = 0; r < 16; r++) oc[cb][r] *= alpha;
        }
        const float nmL = -mm * LOG2E;
        #pragma unroll
        for (int r = 0; r < 16; r++) {
            const float p0 = exp2f(fmaf(S0[r], LOG2E, nmL));
            const float p1 = exp2f(fmaf(S1[r], LOG2E, nmL));
            S0[r] = p0; S1[r] = p1;
            v[r] = p0; v[16 + r] = p1;
        }
        #pragma unroll
        for (int st = 16; st >= 1; st >>= 1)
            #pragma unroll
            for (int i = 0; i < st; i++) v[i] += v[i + st];
        ll += v[0] + __shfl_xor(v[0], 32, 64);

        unsigned int Wl[2][4][2];
        #pragma unroll
        for (int tq = 0; tq < 4; tq++) {
            Wl[0][tq][0] = (unsigned int)f2bf(S0[4 * tq + 0]) | ((unsigned int)f2bf(S0[4 * tq + 1]) << 16);
            Wl[0][tq][1] = (unsigned int)f2bf(S0[4 * tq + 2]) | ((unsigned int)f2bf(S0[4 * tq + 3]) << 16);
            Wl[1][tq][0] = (unsigned int)f2bf(S1[4 * tq + 0]) | ((unsigned int)f2bf(S1[4 * tq + 1]) << 16);
            Wl[1][tq][1] = (unsigned int)f2bf(S1[4 * tq + 2]) | ((unsigned int)f2bf(S1[4 * tq + 3]) << 16);
        }
        #pragma unroll
        for (int ks = 0; ks < 4; ks++) {
            const int kbk = ks >> 1;
            const int te = (ks & 1) * 2, to = te + 1;
            const int a0 = (int)Wl[kbk][te][0], a1 = (int)Wl[kbk][te][1];
            const int b0 = (int)Wl[kbk][to][0], b1 = (int)Wl[kbk][to][1];
            const int xa0 = __shfl_xor(a0, 32, 64);
            const int xa1 = __shfl_xor(a1, 32, 64);
            const int xb0 = __shfl_xor(b0, 32, 64);
            const int xb1 = __shfl_xor(b1, 32, 64);
            WG[ks][0] = (unsigned int)(hi ? xb0 : a0);
            WG[ks][1] = (unsigned int)(hi ? xb1 : a1);
            WG[ks][2] = (unsigned int)(hi ? b0  : xa0);
            WG[ks][3] = (unsigned int)(hi ? b1  : xa1);
        }
    };

    // ---- prologue ----
    stageK(0, 0); stageV(0, 0);
    __syncthreads();
    stageK(1, 1); stageV(1, 1);
    {
        f32x16 SA[2] = {}, SB[2] = {};
        qk(0, SA, SB);
        softmax_pack(0, SA[0], SA[1], mA, lA, oaccA, WpGA);
        softmax_pack(0, SB[0], SB[1], mB, lB, oaccB, WpGB);
    }

    // ---- main pipeline ----
    int vprev = 0, vnext = 2;
    for (int t = 1; t < NT; t++) {
        __syncthreads();
        if (t + 1 < NT) {
            stageK(t + 1, (t + 1) & 1);
            stageV(t + 1, vnext);
        }
        f32x16 SA[2] = {}, SB[2] = {};
        qk(t & 1, SA, SB);
        pv(vprev);
        softmax_pack(t, SA[0], SA[1], mA, lA, oaccA, WpGA);
        softmax_pack(t, SB[0], SB[1], mB, lB, oaccB, WpGB);
        vprev = (vprev == 2) ? 0 : vprev + 1;
        vnext = (vnext == 2) ? 0 : vnext + 1;
    }

    // ---- epilogue ----
    pv(vprev);

    const float invA = 1.f / lA, invB = 1.f / lB;
    const size_t obA = (size_t)qrowA * DIM + h * HD;
    const size_t obB = (size_t)qrowB * DIM + h * HD;
    #pragma unroll
    for (int cb = 0; cb < 4; cb++) {
        #pragma unroll
        for (int tq = 0; tq < 4; tq++) {
            uint2 pa, pb;
            pa.x = (unsigned int)f2bf(oaccA[cb][4 * tq + 0] * invA)
                 | ((unsigned int)f2bf(oaccA[cb][4 * tq + 1] * invA) << 16);
            pa.y = (unsigned int)f2bf(oaccA[cb][4 * tq + 2] * invA)
                 | ((unsigned int)f2bf(oaccA[cb][4 * tq + 3] * invA) << 16);
            pb.x = (unsigned int)f2bf(oaccB[cb][4 * tq + 0] * invB)
                 | ((unsigned int)f2bf(oaccB[cb][4 * tq + 1] * invB) << 16);
            pb.y = (unsigned int)f2bf(oaccB[cb][4 * tq + 2] * invB)
                 | ((unsigned int)f2bf(oaccB[cb][4 * tq + 3] * invB) << 16);
            *reinterpret_cast<uint2*>(&attno[obA + cb * 32 + 8 * tq + 4 * hi]) = pa;
            *reinterpret_cast<uint2*>(&attno[obB + cb * 32 + 8 * tq + 4 * hi]) = pb;
        }
    }
}

// ---------------------------------------------------------------------------
// Output GEMM (m97-style, single-buffered — r21/r23 verified best).
// ---------------------------------------------------------------------------
__global__ __launch_bounds__(256) void gemm_out(
    const __hip_bfloat16* __restrict__ A,
    const __hip_bfloat16* __restrict__ W,
    const float* __restrict__ bias,
    float* __restrict__ outp)
{
    __shared__ __align__(16) short As[128][32];
    __shared__ __align__(16) short Bs[128][32];
    const int bm0 = blockIdx.x * 128;
    const int bn0 = blockIdx.y * 128;
    const int tid = threadIdx.x;
    const int lane = tid & 63;
    const int wid = tid >> 6;
    const int wm = (wid >> 1) * 64;
    const int wn = (wid & 1) * 64;
    const int fr = lane & 15;
    const int fc = (lane >> 4) * 8;
    const int srow = tid >> 2;
    const int scol = (tid & 3) * 8;

    f32x4 acc[4][4] = {};

    for (int kt = 0; kt < DIM; kt += 32) {
        #pragma unroll
        for (int i = 0; i < 2; i++) {
            async_cp16(&As[i * 64 + (wid << 4)][0],
                       A + (size_t)(bm0 + i * 64 + srow) * DIM + kt + scol);
            async_cp16(&Bs[i * 64 + (wid << 4)][0],
                       W + (size_t)(bn0 + i * 64 + srow) * DIM + kt + scol);
        }
        __syncthreads();
        short8 af[4], bf8[4];
        #pragma unroll
        for (int m = 0; m < 4; m++) af[m]  = *reinterpret_cast<const short8*>(&As[wm + m * 16 + fr][fc]);
        #pragma unroll
        for (int n = 0; n < 4; n++) bf8[n] = *reinterpret_cast<const short8*>(&Bs[wn + n * 16 + fr][fc]);
        #pragma unroll
        for (int m = 0; m < 4; m++)
            #pragma unroll
            for (int n = 0; n < 4; n++)
                acc[m][n] = __builtin_amdgcn_mfma_f32_16x16x32_bf16(af[m], bf8[n], acc[m][n], 0, 0, 0);
        __syncthreads();
    }

    const int crow0 = bm0 + wm + (lane >> 4) * 4;
    const int ccol0 = bn0 + wn + fr;
    #pragma unroll
    for (int n = 0; n < 4; n++) {
        const int col = ccol0 + n * 16;
        const float bb = bias[col];
        #pragma unroll
        for (int m = 0; m < 4; m++)
            #pragma unroll
            for (int r = 0; r < 4; r++)
                outp[(size_t)(crow0 + m * 16 + r) * DIM + col] = acc[m][n][r] + bb;
    }
}

// ---------------------------------------------------------------------------
extern "C" void kernel_launch(void* const* d_in, const int* in_sizes, int n_in,
                              void* d_out, int out_size, void* d_ws, size_t ws_size,
                              hipStream_t stream)
{
    const float* x        = (const float*)d_in[0];
    const int*   seq_lens = (const int*)d_in[1];
    const float* freqs    = (const float*)d_in[3];
    const float* wq = (const float*)d_in[4];
    const float* bq = (const float*)d_in[5];
    const float* wk = (const float*)d_in[6];
    const float* bk = (const float*)d_in[7];
    const float* wv = (const float*)d_in[8];
    const float* bv = (const float*)d_in[9];
    const float* wo = (const float*)d_in[10];
    const float* bo = (const float*)d_in[11];
    const float* gq = (const float*)d_in[12];
    const float* gk = (const float*)d_in[13];
    float* out = (float*)d_out;

    // workspace (50,331,648 bytes) + d_out used as early scratch:
    //   yq bf16 [0, 12582912)          (q; dead after flash -> wob aliases)
    //   yk bf16 [12582912, 25165824)
    //   vrow bf16 [25165824, 37748736) (dead after transpose; attno aliases)
    //   vT bf16 [37748736, 50331648)   (xb lives here until transpose)
    //   wq/wk/wv bf16 -> d_out scratch (until gemm_out writes)
    char* ws = (char*)d_ws;
    __hip_bfloat16* yq    = (__hip_bfloat16*)(ws);
    __hip_bfloat16* yk    = (__hip_bfloat16*)(ws + 12582912);
    __hip_bfloat16* vrow  = (__hip_bfloat16*)(ws + 25165824);
    __hip_bfloat16* vT    = (__hip_bfloat16*)(ws + 37748736);
    __hip_bfloat16* attno = (__hip_bfloat16*)(ws + 25165824);
    __hip_bfloat16* xb    = (__hip_bfloat16*)(ws + 37748736);
    __hip_bfloat16* wob   = (__hip_bfloat16*)(ws);
    __hip_bfloat16* wqb   = (__hip_bfloat16*)d_out;
    __hip_bfloat16* wkb   = wqb + 2359296;
    __hip_bfloat16* wvb   = wkb + 2359296;

    dim3 blk(256);
    convert_all        <<<dim3(6528), blk, 0, stream>>>(x, wq, wk, wv, xb, wqb, wkb, wvb);
    gemm_qkv           <<<dim3(32, 12, 3), blk, 0, stream>>>(xb, wqb, bq, wkb, bk, wvb, bv, yq, yk, vrow);
    norm_rope_transpose<<<dim3(9728), blk, 0, stream>>>(yq, yk, gq, gk, freqs, vrow, vT);
    flash_attn         <<<dim3(32, 12), dim3(128), 0, stream>>>(yq, yk, vT, seq_lens, attno);
    convert_bf16       <<<dim3(1152), blk, 0, stream>>>(wo, wob, 294912);
    gemm_out           <<<dim3(32, 12), blk, 0, stream>>>(attno, wob, bo, out);
}

// Round 25
// 323.142 us; speedup vs baseline: 1.2574x; 1.2574x over previous
//
#include <hip/hip_runtime.h>
#include <hip/hip_bf16.h>

#define DIM   1536
#define HEADS 12
#define HD    128
#define SEQ   4096
#define QSCALE 0.08838834764831845f
#define LOG2E 1.44269504088896f

typedef __attribute__((ext_vector_type(8))) short short8;
typedef __attribute__((ext_vector_type(4))) float f32x4;
typedef __attribute__((ext_vector_type(16))) float f32x16;

__device__ __forceinline__ unsigned short f2bf(float f) {
    __hip_bfloat16 h = __float2bfloat16(f);
    return *reinterpret_cast<unsigned short*>(&h);
}
__device__ __forceinline__ float bf2f(unsigned short u) {
    return __uint_as_float(((unsigned int)u) << 16);
}
__device__ __forceinline__ void async_cp16(void* lds, const void* g) {
    __builtin_amdgcn_global_load_lds(
        (const __attribute__((address_space(1))) unsigned int*)g,
        (__attribute__((address_space(3))) unsigned int*)lds, 16, 0, 0);
}

// ---------------------------------------------------------------------------
// f32 -> bf16 convert, 8 elements/thread. (for wo, post-flash)
// ---------------------------------------------------------------------------
__global__ __launch_bounds__(256) void convert_bf16(
    const float* __restrict__ src, __hip_bfloat16* __restrict__ dst, int n8)
{
    const int i = blockIdx.x * 256 + threadIdx.x;
    if (i >= n8) return;
    const float4 a = *reinterpret_cast<const float4*>(src + (size_t)i * 8);
    const float4 b = *reinterpret_cast<const float4*>(src + (size_t)i * 8 + 4);
    uint4 o;
    o.x = (unsigned int)f2bf(a.x) | ((unsigned int)f2bf(a.y) << 16);
    o.y = (unsigned int)f2bf(a.z) | ((unsigned int)f2bf(a.w) << 16);
    o.z = (unsigned int)f2bf(b.x) | ((unsigned int)f2bf(b.y) << 16);
    o.w = (unsigned int)f2bf(b.z) | ((unsigned int)f2bf(b.w) << 16);
    *reinterpret_cast<uint4*>(dst + (size_t)i * 8) = o;
}

// ---------------------------------------------------------------------------
// Batched f32 -> bf16 convert: x, wq, wk, wv in one launch. (verified r20)
// ---------------------------------------------------------------------------
__global__ __launch_bounds__(256) void convert_all(
    const float* __restrict__ x,  const float* __restrict__ wq,
    const float* __restrict__ wk, const float* __restrict__ wv,
    __hip_bfloat16* __restrict__ xb,  __hip_bfloat16* __restrict__ wqb,
    __hip_bfloat16* __restrict__ wkb, __hip_bfloat16* __restrict__ wvb)
{
    const int i = blockIdx.x * 256 + threadIdx.x;   // grid covers 1671168
    const float* src;
    __hip_bfloat16* dst;
    int off;
    if (i < 786432)            { src = x;  dst = xb;  off = i; }
    else if (i < 1081344)      { src = wq; dst = wqb; off = i - 786432; }
    else if (i < 1376256)      { src = wk; dst = wkb; off = i - 1081344; }
    else                       { src = wv; dst = wvb; off = i - 1376256; }
    const float4 a = *reinterpret_cast<const float4*>(src + (size_t)off * 8);
    const float4 b = *reinterpret_cast<const float4*>(src + (size_t)off * 8 + 4);
    uint4 o;
    o.x = (unsigned int)f2bf(a.x) | ((unsigned int)f2bf(a.y) << 16);
    o.y = (unsigned int)f2bf(a.z) | ((unsigned int)f2bf(a.w) << 16);
    o.z = (unsigned int)f2bf(b.x) | ((unsigned int)f2bf(b.y) << 16);
    o.w = (unsigned int)f2bf(b.z) | ((unsigned int)f2bf(b.w) << 16);
    *reinterpret_cast<uint4*>(dst + (size_t)off * 8) = o;
}

// ---------------------------------------------------------------------------
// GEMM (m97-style, single-buffered — r21/r23 verified best).
// ---------------------------------------------------------------------------
__global__ __launch_bounds__(256) void gemm_qkv(
    const __hip_bfloat16* __restrict__ xb,
    const __hip_bfloat16* __restrict__ wqb, const float* __restrict__ bq,
    const __hip_bfloat16* __restrict__ wkb, const float* __restrict__ bk,
    const __hip_bfloat16* __restrict__ wvb, const float* __restrict__ bv,
    __hip_bfloat16* __restrict__ yq, __hip_bfloat16* __restrict__ yk,
    __hip_bfloat16* __restrict__ vrow)
{
    __shared__ __align__(16) short As[128][32];
    __shared__ __align__(16) short Bs[128][32];
    const int z  = blockIdx.z;
    const __hip_bfloat16* W = (z == 0) ? wqb : (z == 1) ? wkb : wvb;
    const float* bias = (z == 0) ? bq : (z == 1) ? bk : bv;
    __hip_bfloat16* outp = (z == 0) ? yq : (z == 1) ? yk : vrow;
    const int bm0 = blockIdx.x * 128;
    const int bn0 = blockIdx.y * 128;
    const int tid  = threadIdx.x;
    const int lane = tid & 63;
    const int wid  = tid >> 6;
    const int wm = (wid >> 1) * 64;
    const int wn = (wid & 1)  * 64;
    const int fr = lane & 15;
    const int fc = (lane >> 4) * 8;
    const int srow = tid >> 2;
    const int scol = (tid & 3) * 8;

    f32x4 acc[4][4] = {};

    for (int kt = 0; kt < DIM; kt += 32) {
        #pragma unroll
        for (int i = 0; i < 2; i++) {
            async_cp16(&As[i * 64 + (wid << 4)][0],
                       xb + (size_t)(bm0 + i * 64 + srow) * DIM + kt + scol);
            async_cp16(&Bs[i * 64 + (wid << 4)][0],
                       W + (size_t)(bn0 + i * 64 + srow) * DIM + kt + scol);
        }
        __syncthreads();
        short8 af[4], bf8[4];
        #pragma unroll
        for (int m = 0; m < 4; m++) af[m]  = *reinterpret_cast<const short8*>(&As[wm + m * 16 + fr][fc]);
        #pragma unroll
        for (int n = 0; n < 4; n++) bf8[n] = *reinterpret_cast<const short8*>(&Bs[wn + n * 16 + fr][fc]);
        #pragma unroll
        for (int m = 0; m < 4; m++)
            #pragma unroll
            for (int n = 0; n < 4; n++)
                acc[m][n] = __builtin_amdgcn_mfma_f32_16x16x32_bf16(af[m], bf8[n], acc[m][n], 0, 0, 0);
        __syncthreads();
    }

    const int crow0 = bm0 + wm + (lane >> 4) * 4;
    const int ccol0 = bn0 + wn + fr;
    #pragma unroll
    for (int n = 0; n < 4; n++) {
        const int col = ccol0 + n * 16;
        const float bb = bias[col];
        #pragma unroll
        for (int m = 0; m < 4; m++)
            #pragma unroll
            for (int r = 0; r < 4; r++)
                outp[(size_t)(crow0 + m * 16 + r) * DIM + col] =
                    __float2bfloat16(acc[m][n][r] + bb);
    }
}

// ---------------------------------------------------------------------------
// Merged: RMSNorm+RoPE (blocks 0..8191) and V-transpose (8192..9727).
// (unchanged, verified r21)
// ---------------------------------------------------------------------------
__global__ __launch_bounds__(256) void norm_rope_transpose(
    __hip_bfloat16* __restrict__ yq, __hip_bfloat16* __restrict__ yk,
    const float* __restrict__ gq, const float* __restrict__ gk,
    const float* __restrict__ freqs,
    const __hip_bfloat16* __restrict__ vrow, __hip_bfloat16* __restrict__ vT)
{
    __shared__ float red[4];
    __shared__ __align__(16) short tile[64][72];
    const int b = blockIdx.x;
    const int t = threadIdx.x;

    if (b < 8192) {
        const int s = b >> 1;
        const int z = b & 1;
        __hip_bfloat16* y = z ? yk : yq;
        const float* g = z ? gk : gq;

        float xr[3], xi[3];
        float ss = 0.f;
        #pragma unroll
        for (int i = 0; i < 3; i++) {
            const int p = t + i * 256;
            const unsigned int uu = *reinterpret_cast<const unsigned int*>(&y[(size_t)s * DIM + 2 * p]);
            xr[i] = bf2f((unsigned short)(uu & 0xffffu));
            xi[i] = bf2f((unsigned short)(uu >> 16));
            ss += xr[i] * xr[i] + xi[i] * xi[i];
        }
        #pragma unroll
        for (int m = 1; m < 64; m <<= 1) ss += __shfl_xor(ss, m, 64);
        if ((t & 63) == 0) red[t >> 6] = ss;
        __syncthreads();
        const float sum = red[0] + red[1] + red[2] + red[3];
        const float rs = rsqrtf(sum * (1.0f / DIM) + 1e-6f);
        const int f = s >> 8, hh = (s >> 4) & 15, ww = s & 15;
        const float osc = z ? 1.0f : QSCALE;
        #pragma unroll
        for (int i = 0; i < 3; i++) {
            const int p = t + i * 256;
            const int cc = p & 63;
            const int pos = (cc < 22) ? f : (cc < 43) ? hh : ww;
            const float ang = freqs[pos * 64 + cc];
            float sn, cs;
            sincosf(ang, &sn, &cs);
            const float a = xr[i] * rs * g[2 * p];
            const float bb = xi[i] * rs * g[2 * p + 1];
            const unsigned int pk = (unsigned int)f2bf((a * cs - bb * sn) * osc)
                                  | ((unsigned int)f2bf((a * sn + bb * cs) * osc) << 16);
            *reinterpret_cast<unsigned int*>(&y[(size_t)s * DIM + 2 * p]) = pk;
        }
    } else {
        const int tb = b - 8192;
        const int s0 = (tb & 63) * 64;
        const int c0 = (tb >> 6) * 64;
        #pragma unroll
        for (int i = 0; i < 2; i++) {
            const int ch = t + i * 256;
            const int r = ch >> 3, cc = (ch & 7) * 8;
            *reinterpret_cast<int4*>(&tile[r][cc]) =
                *reinterpret_cast<const int4*>(&vrow[(size_t)(s0 + r) * DIM + c0 + cc]);
        }
        __syncthreads();
        #pragma unroll
        for (int i = 0; i < 2; i++) {
            const int ch = t + i * 256;
            const int c = ch & 63, sc = (ch >> 6) * 8;
            unsigned int w0 = (unsigned short)tile[sc + 0][c] | ((unsigned int)(unsigned short)tile[sc + 1][c] << 16);
            unsigned int w1 = (unsigned short)tile[sc + 2][c] | ((unsigned int)(unsigned short)tile[sc + 3][c] << 16);
            unsigned int w2 = (unsigned short)tile[sc + 4][c] | ((unsigned int)(unsigned short)tile[sc + 5][c] << 16);
            unsigned int w3 = (unsigned short)tile[sc + 6][c] | ((unsigned int)(unsigned short)tile[sc + 7][c] << 16);
            int4 val;
            val.x = (int)w0; val.y = (int)w1; val.z = (int)w2; val.w = (int)w3;
            *reinterpret_cast<int4*>(&vT[(size_t)(c0 + c) * SEQ + s0 + sc]) = val;
        }
    }
}

// ---------------------------------------------------------------------------
// Flash attention v13 (r21/r23 verified best; 200-205us plateau)
// ---------------------------------------------------------------------------
__global__ __launch_bounds__(256, 2) void flash_attn(
    const __hip_bfloat16* __restrict__ qb,
    const __hip_bfloat16* __restrict__ kb,
    const __hip_bfloat16* __restrict__ vT,
    const int* __restrict__ seq_lens,
    __hip_bfloat16* __restrict__ attno)
{
    __shared__ __align__(16) short Ks[2][64][128];   // 32 KB
    __shared__ __align__(16) short Vs[3][128][64];   // 48 KB
    const int qt = blockIdx.x;
    const int h  = blockIdx.y;
    const int tid = threadIdx.x;
    const int lane = tid & 63;
    const int w = tid >> 6;
    const int q5 = lane & 31;
    const int hi = lane >> 5;
    const int seqlen = seq_lens[0];
    const int swz = (lane & 7) << 4;
    const int NT = SEQ / 64;

    short8 qf[8];
    const int qrow = qt * 128 + w * 32 + q5;
    #pragma unroll
    for (int s = 0; s < 8; s++)
        qf[s] = *reinterpret_cast<const short8*>(&qb[(size_t)qrow * DIM + h * HD + s * 16 + hi * 8]);

    f32x16 oacc[4] = {};
    float m = -1e30f, l = 0.f;
    unsigned int WpG[4][4];

    const int kROW = w * 4 + (lane >> 4);
    const int kCOL = ((lane & 15) ^ (kROW & 7)) * 8;
    const int vROW = w * 8 + (lane >> 3);
    const int vCOL = (((lane & 7) ^ (vROW & 7))) * 8;

    auto stageK = [&](int tile, int slot) {
        #pragma unroll
        for (int i = 0; i < 4; i++)
            async_cp16(&Ks[slot][i * 16 + w * 4][0],
                       kb + (size_t)(tile * 64 + i * 16 + kROW) * DIM + h * HD + kCOL);
    };
    auto stageV = [&](int tile, int slot) {
        #pragma unroll
        for (int i = 0; i < 4; i++)
            async_cp16(&Vs[slot][i * 32 + vROW][0],
                       vT + ((size_t)h * HD + i * 32 + vROW) * SEQ + tile * 64 + vCOL);
    };
    auto pv = [&](int slot) {
        const char* Vp = (const char*)&Vs[slot][0][0];
        __builtin_amdgcn_s_setprio(1);
        #pragma unroll
        for (int ks = 0; ks < 4; ks++) {
            int4 pwv;
            pwv.x = (int)WpG[ks][0];
            pwv.y = (int)WpG[ks][1];
            pwv.z = (int)WpG[ks][2];
            pwv.w = (int)WpG[ks][3];
            const short8 pf = __builtin_bit_cast(short8, pwv);
            #pragma unroll
            for (int cb = 0; cb < 4; cb++) {
                short8 vf = *reinterpret_cast<const short8*>(
                    Vp + (cb * 32 + q5) * 128 + ((ks * 32 + hi * 16) ^ swz));
                oacc[cb] = __builtin_amdgcn_mfma_f32_32x32x16_bf16(vf, pf, oacc[cb], 0, 0, 0);
            }
        }
        __builtin_amdgcn_s_setprio(0);
    };
    auto softmax_pack = [&](int tt, f32x16* S) {
        const int kbase = tt * 64;
        float v[32];
        if (kbase + 64 <= seqlen) {
            #pragma unroll
            for (int kbk = 0; kbk < 2; kbk++)
                #pragma unroll
                for (int r = 0; r < 16; r++) v[kbk * 16 + r] = S[kbk][r];
        } else {
            #pragma unroll
            for (int kbk = 0; kbk < 2; kbk++)
                #pragma unroll
                for (int r = 0; r < 16; r++) {
                    const int key = kbase + kbk * 32 + (r & 3) + 8 * (r >> 2) + 4 * hi;
                    const float sv = (key < seqlen) ? S[kbk][r] : -1e30f;
                    S[kbk][r] = sv;
                    v[kbk * 16 + r] = sv;
                }
        }
        #pragma unroll
        for (int st = 16; st >= 1; st >>= 1)
            #pragma unroll
            for (int i = 0; i < st; i++) v[i] = fmaxf(v[i], v[i + st]);
        float tmax = fmaxf(v[0], __shfl_xor(v[0], 32, 64));

        if (!__all(tmax <= m + 8.0f)) {
            const float mn = fmaxf(m, tmax);
            const float alpha = exp2f((m - mn) * LOG2E);
            m = mn;
            l *= alpha;
            #pragma unroll
            for (int cb = 0; cb < 4; cb++)
                #pragma unroll
                for (int r = 0; r < 16; r++) oacc[cb][r] *= alpha;
        }
        const float nmL = -m * LOG2E;
        #pragma unroll
        for (int kbk = 0; kbk < 2; kbk++)
            #pragma unroll
            for (int r = 0; r < 16; r++) {
                const float p = exp2f(fmaf(S[kbk][r], LOG2E, nmL));
                S[kbk][r] = p;
                v[kbk * 16 + r] = p;
            }
        #pragma unroll
        for (int st = 16; st >= 1; st >>= 1)
            #pragma unroll
            for (int i = 0; i < st; i++) v[i] += v[i + st];
        l += v[0] + __shfl_xor(v[0], 32, 64);

        unsigned int Wl[2][4][2];
        #pragma unroll
        for (int kbk = 0; kbk < 2; kbk++)
            #pragma unroll
            for (int tq = 0; tq < 4; tq++) {
                Wl[kbk][tq][0] = (unsigned int)f2bf(S[kbk][4 * tq + 0])
                               | ((unsigned int)f2bf(S[kbk][4 * tq + 1]) << 16);
                Wl[kbk][tq][1] = (unsigned int)f2bf(S[kbk][4 * tq + 2])
                               | ((unsigned int)f2bf(S[kbk][4 * tq + 3]) << 16);
            }
        #pragma unroll
        for (int ks = 0; ks < 4; ks++) {
            const int kbk = ks >> 1;
            const int te = (ks & 1) * 2, to = te + 1;
            const int a0 = (int)Wl[kbk][te][0], a1 = (int)Wl[kbk][te][1];
            const int b0 = (int)Wl[kbk][to][0], b1 = (int)Wl[kbk][to][1];
            const int xa0 = __shfl_xor(a0, 32, 64);
            const int xa1 = __shfl_xor(a1, 32, 64);
            const int xb0 = __shfl_xor(b0, 32, 64);
            const int xb1 = __shfl_xor(b1, 32, 64);
            WpG[ks][0] = (unsigned int)(hi ? xb0 : a0);
            WpG[ks][1] = (unsigned int)(hi ? xb1 : a1);
            WpG[ks][2] = (unsigned int)(hi ? b0  : xa0);
            WpG[ks][3] = (unsigned int)(hi ? b1  : xa1);
        }
    };
    auto qk = [&](int slot, f32x16* S) {
        const char* Kp = (const char*)&Ks[slot][0][0];
        __builtin_amdgcn_s_setprio(1);
        #pragma unroll
        for (int s = 0; s < 8; s++)
            #pragma unroll
            for (int kbk = 0; kbk < 2; kbk++) {
                short8 kf = *reinterpret_cast<const short8*>(
                    Kp + (kbk * 32 + q5) * 256 + ((s * 32 + hi * 16) ^ swz));
                S[kbk] = __builtin_amdgcn_mfma_f32_32x32x16_bf16(kf, qf[s], S[kbk], 0, 0, 0);
            }
        __builtin_amdgcn_s_setprio(0);
    };

    stageK(0, 0); stageV(0, 0);
    __syncthreads();
    stageK(1, 1); stageV(1, 1);
    {
        f32x16 sacc[2] = {};
        qk(0, sacc);
        softmax_pack(0, sacc);
    }

    int vprev = 0, vnext = 2;
    for (int t = 1; t < NT; t++) {
        __syncthreads();
        if (t + 1 < NT) {
            stageK(t + 1, (t + 1) & 1);
            stageV(t + 1, vnext);
        }
        f32x16 sacc[2] = {};
        qk(t & 1, sacc);
        pv(vprev);
        softmax_pack(t, sacc);
        vprev = (vprev == 2) ? 0 : vprev + 1;
        vnext = (vnext == 2) ? 0 : vnext + 1;
    }

    pv(vprev);

    const float inv_l = 1.f / l;
    const size_t obase = (size_t)qrow * DIM + h * HD;
    #pragma unroll
    for (int cb = 0; cb < 4; cb++) {
        #pragma unroll
        for (int tq = 0; tq < 4; tq++) {
            uint2 pko;
            pko.x = (unsigned int)f2bf(oacc[cb][4 * tq + 0] * inv_l)
                  | ((unsigned int)f2bf(oacc[cb][4 * tq + 1] * inv_l) << 16);
            pko.y = (unsigned int)f2bf(oacc[cb][4 * tq + 2] * inv_l)
                  | ((unsigned int)f2bf(oacc[cb][4 * tq + 3] * inv_l) << 16);
            *reinterpret_cast<uint2*>(&attno[obase + cb * 32 + 8 * tq + 4 * hi]) = pko;
        }
    }
}

// ---------------------------------------------------------------------------
// Output GEMM (m97-style, single-buffered — r21/r23 verified best).
// ---------------------------------------------------------------------------
__global__ __launch_bounds__(256) void gemm_out(
    const __hip_bfloat16* __restrict__ A,
    const __hip_bfloat16* __restrict__ W,
    const float* __restrict__ bias,
    float* __restrict__ outp)
{
    __shared__ __align__(16) short As[128][32];
    __shared__ __align__(16) short Bs[128][32];
    const int bm0 = blockIdx.x * 128;
    const int bn0 = blockIdx.y * 128;
    const int tid = threadIdx.x;
    const int lane = tid & 63;
    const int wid = tid >> 6;
    const int wm = (wid >> 1) * 64;
    const int wn = (wid & 1) * 64;
    const int fr = lane & 15;
    const int fc = (lane >> 4) * 8;
    const int srow = tid >> 2;
    const int scol = (tid & 3) * 8;

    f32x4 acc[4][4] = {};

    for (int kt = 0; kt < DIM; kt += 32) {
        #pragma unroll
        for (int i = 0; i < 2; i++) {
            async_cp16(&As[i * 64 + (wid << 4)][0],
                       A + (size_t)(bm0 + i * 64 + srow) * DIM + kt + scol);
            async_cp16(&Bs[i * 64 + (wid << 4)][0],
                       W + (size_t)(bn0 + i * 64 + srow) * DIM + kt + scol);
        }
        __syncthreads();
        short8 af[4], bf8[4];
        #pragma unroll
        for (int m = 0; m < 4; m++) af[m]  = *reinterpret_cast<const short8*>(&As[wm + m * 16 + fr][fc]);
        #pragma unroll
        for (int n = 0; n < 4; n++) bf8[n] = *reinterpret_cast<const short8*>(&Bs[wn + n * 16 + fr][fc]);
        #pragma unroll
        for (int m = 0; m < 4; m++)
            #pragma unroll
            for (int n = 0; n < 4; n++)
                acc[m][n] = __builtin_amdgcn_mfma_f32_16x16x32_bf16(af[m], bf8[n], acc[m][n], 0, 0, 0);
        __syncthreads();
    }

    const int crow0 = bm0 + wm + (lane >> 4) * 4;
    const int ccol0 = bn0 + wn + fr;
    #pragma unroll
    for (int n = 0; n < 4; n++) {
        const int col = ccol0 + n * 16;
        const float bb = bias[col];
        #pragma unroll
        for (int m = 0; m < 4; m++)
            #pragma unroll
            for (int r = 0; r < 4; r++)
                outp[(size_t)(crow0 + m * 16 + r) * DIM + col] = acc[m][n][r] + bb;
    }
}

// ---------------------------------------------------------------------------
extern "C" void kernel_launch(void* const* d_in, const int* in_sizes, int n_in,
                              void* d_out, int out_size, void* d_ws, size_t ws_size,
                              hipStream_t stream)
{
    const float* x        = (const float*)d_in[0];
    const int*   seq_lens = (const int*)d_in[1];
    const float* freqs    = (const float*)d_in[3];
    const float* wq = (const float*)d_in[4];
    const float* bq = (const float*)d_in[5];
    const float* wk = (const float*)d_in[6];
    const float* bk = (const float*)d_in[7];
    const float* wv = (const float*)d_in[8];
    const float* bv = (const float*)d_in[9];
    const float* wo = (const float*)d_in[10];
    const float* bo = (const float*)d_in[11];
    const float* gq = (const float*)d_in[12];
    const float* gk = (const float*)d_in[13];
    float* out = (float*)d_out;

    // workspace (50,331,648 bytes) + d_out used as early scratch:
    //   yq bf16 [0, 12582912)          (q; dead after flash -> wob aliases)
    //   yk bf16 [12582912, 25165824)
    //   vrow bf16 [25165824, 37748736) (dead after transpose; attno aliases)
    //   vT bf16 [37748736, 50331648)   (xb lives here until transpose)
    //   wq/wk/wv bf16 -> d_out scratch (until gemm_out writes)
    char* ws = (char*)d_ws;
    __hip_bfloat16* yq    = (__hip_bfloat16*)(ws);
    __hip_bfloat16* yk    = (__hip_bfloat16*)(ws + 12582912);
    __hip_bfloat16* vrow  = (__hip_bfloat16*)(ws + 25165824);
    __hip_bfloat16* vT    = (__hip_bfloat16*)(ws + 37748736);
    __hip_bfloat16* attno = (__hip_bfloat16*)(ws + 25165824);
    __hip_bfloat16* xb    = (__hip_bfloat16*)(ws + 37748736);
    __hip_bfloat16* wob   = (__hip_bfloat16*)(ws);
    __hip_bfloat16* wqb   = (__hip_bfloat16*)d_out;
    __hip_bfloat16* wkb   = wqb + 2359296;
    __hip_bfloat16* wvb   = wkb + 2359296;

    dim3 blk(256);
    convert_all        <<<dim3(6528), blk, 0, stream>>>(x, wq, wk, wv, xb, wqb, wkb, wvb);
    gemm_qkv           <<<dim3(32, 12, 3), blk, 0, stream>>>(xb, wqb, bq, wkb, bk, wvb, bv, yq, yk, vrow);
    norm_rope_transpose<<<dim3(9728), blk, 0, stream>>>(yq, yk, gq, gk, freqs, vrow, vT);
    flash_attn         <<<dim3(32, 12), blk, 0, stream>>>(yq, yk, vT, seq_lens, attno);
    convert_bf16       <<<dim3(1152), blk, 0, stream>>>(wo, wob, 294912);
    gemm_out           <<<dim3(32, 12), blk, 0, stream>>>(attno, wob, bo, out);
}